// Round 6
// baseline (376.323 us; speedup 1.0000x reference)
//
#include <hip/hip_runtime.h>

#define N_SUM 2048
#define HIDD 128
#define NEDGE 16384
#define ROWS (N_SUM * 64)

typedef short short8 __attribute__((ext_vector_type(8)));
typedef float floatx4 __attribute__((ext_vector_type(4)));
typedef float float2v __attribute__((ext_vector_type(2)));
typedef unsigned int uint4n __attribute__((ext_vector_type(4)));
typedef unsigned short ushort_t;

__device__ __forceinline__ ushort_t f2bf(float f) {
    unsigned u = __builtin_bit_cast(unsigned, f);
    u += 0x7fffu + ((u >> 16) & 1u);   // RNE
    return (ushort_t)(u >> 16);
}
__device__ __forceinline__ float bf2f(ushort_t h) {
    return __builtin_bit_cast(float, (unsigned)h << 16);
}
// uint32 holding two bf16 -> float2 (elem0 = low half, elem1 = high half)
__device__ __forceinline__ float2v bfpair(unsigned u) {
    float2v r;
    r.x = __builtin_bit_cast(float, u << 16);
    r.y = __builtin_bit_cast(float, u & 0xffff0000u);
    return r;
}
__device__ __forceinline__ void unpack8(uint4 v, float* f) {
    f[0] = bf2f(v.x & 0xffff); f[1] = bf2f(v.x >> 16);
    f[2] = bf2f(v.y & 0xffff); f[3] = bf2f(v.y >> 16);
    f[4] = bf2f(v.z & 0xffff); f[5] = bf2f(v.z >> 16);
    f[6] = bf2f(v.w & 0xffff); f[7] = bf2f(v.w >> 16);
}
__device__ __forceinline__ uint4 pack8(const float* f) {
    uint4 v;
    v.x = f2bf(f[0]) | ((unsigned)f2bf(f[1]) << 16);
    v.y = f2bf(f[2]) | ((unsigned)f2bf(f[3]) << 16);
    v.z = f2bf(f[4]) | ((unsigned)f2bf(f[5]) << 16);
    v.w = f2bf(f[6]) | ((unsigned)f2bf(f[7]) << 16);
    return v;
}
__device__ __forceinline__ void nt_store16(const void* src, void* dst) {
    __builtin_nontemporal_store(*(const uint4n*)src, (uint4n*)dst);
}

// ---------------- CSR build ----------------
__global__ __launch_bounds__(256) void zero_ints(int* p, int n) {
    int i = blockIdx.x * 256 + threadIdx.x;
    if (i < n) p[i] = 0;
}

__global__ __launch_bounds__(256) void count_deg(const int* __restrict__ dst, int* __restrict__ deg) {
    int e = blockIdx.x * 256 + threadIdx.x;
    if (e < NEDGE) atomicAdd(&deg[dst[e]], 1);
}

__global__ __launch_bounds__(256) void scan_deg(const int* __restrict__ deg, int* __restrict__ row_ptr) {
    __shared__ int csum[256];
    int t = threadIdx.x;
    int loc[8];
    int s = 0;
#pragma unroll
    for (int q = 0; q < 8; q++) { loc[q] = s; s += deg[t * 8 + q]; }
    csum[t] = s;
    __syncthreads();
    for (int off = 1; off < 256; off <<= 1) {
        int v = (t >= off) ? csum[t - off] : 0;
        __syncthreads();
        csum[t] += v;
        __syncthreads();
    }
    int base = (t == 0) ? 0 : csum[t - 1];
#pragma unroll
    for (int q = 0; q < 8; q++) row_ptr[t * 8 + q] = base + loc[q];
    if (t == 255) row_ptr[2048] = csum[255];
}

__global__ __launch_bounds__(256) void fill_csr(const int* __restrict__ src, const int* __restrict__ dst,
                                                const int* __restrict__ row_ptr, int* __restrict__ cursor,
                                                int* __restrict__ col) {
    int e = blockIdx.x * 256 + threadIdx.x;
    if (e < NEDGE) {
        int d = dst[e];
        int pos = atomicAdd(&cursor[d], 1);
        col[row_ptr[d] + pos] = src[e];
    }
}

// ---------------- weight prep ----------------
__global__ __launch_bounds__(256) void prep_small(const float* __restrict__ W1f, const float* __restrict__ W2l,
                                                  const float* __restrict__ b2m, const float* __restrict__ W1r,
                                                  ushort_t* __restrict__ w1t0, ushort_t* __restrict__ w2lt,
                                                  float* __restrict__ bvec) {
    int idx = blockIdx.x * 256 + threadIdx.x;
    if (idx < 4096) {
        int nn = idx >> 5, k = idx & 31;
        w1t0[idx] = f2bf(k < 16 ? W1f[k * 128 + nn] : 0.f);
    } else if (idx < 4096 + 8192) {
        int r = idx - 4096;
        int nn = r >> 7, k = r & 127;
        w2lt[r] = f2bf(W2l[k * 64 + nn]);
    } else if (idx < 4096 + 8192 + 384) {
        int r = idx - 12288;
        int lm = r >> 7, c = r & 127;
        float s = 0.f;
        for (int o = 0; o < 128; o++) s += b2m[lm * 128 + o] * W1r[(size_t)lm * 16384 + o * 128 + c];
        bvec[r] = s;
    }
}

// w21t[lm][c][i] = bf16( sum_o W2m[lm][i][o] * W1r[lm][o][c] )  -- B-fragment layout [n=c][k=i]
__global__ __launch_bounds__(256) void prep_w21(const float* __restrict__ W2m, const float* __restrict__ W1r,
                                                ushort_t* __restrict__ w21t) {
    int idx = blockIdx.x * 256 + threadIdx.x;  // 49152 total
    int lm = idx >> 14, r = idx & 16383, i = r >> 7, c = r & 127;
    const float* w2row = W2m + (size_t)lm * 16384 + i * 128;
    const float* w1col = W1r + (size_t)lm * 16384 + c;
    float s = 0.f;
#pragma unroll 8
    for (int o = 0; o < 128; o++) s += w2row[o] * w1col[o * 128];
    w21t[(size_t)lm * 16384 + c * 128 + i] = f2bf(s);
}

// A-layout for a 64x128 (or 64x32) bf16 tile: elem(m, k) at ((k>>3)*64 + m)*8 + (k&7)

// ---------------- layer 0: gather fp32 W + MFMA (K=16 padded to 32) ----------------
// BN stats accumulated via atomicAdd into sums0[256] (sum | sumsq)
__global__ __launch_bounds__(256, 4) void gin_mm1_l0(const float* __restrict__ Xf, const ushort_t* __restrict__ W1t,
                                                     const float* __restrict__ b1, const float* __restrict__ eps,
                                                     const int* __restrict__ rp, const int* __restrict__ colv,
                                                     ushort_t* __restrict__ H, float* __restrict__ sums) {
    __shared__ ushort_t Zs[64 * 128];  // 16 KB
    int tid = threadIdx.x, n = blockIdx.x;
    float ev = 1.0f + eps[0];
    int e0 = rp[n], e1 = rp[n + 1], deg = e1 - e0;
    const float4* X = (const float4*)Xf;

    // 4-deep ring gather (slab = 256 float4, 1 per thread)
    float4 r0, r1, r2, r3;
    r0 = X[(size_t)n * 256 + tid];
    if (deg > 0) r1 = X[(size_t)colv[e0] * 256 + tid];
    if (deg > 1) r2 = X[(size_t)colv[e0 + 1] * 256 + tid];
    if (deg > 2) r3 = X[(size_t)colv[e0 + 2] * 256 + tid];
    float4 a;
    a.x = r0.x * ev; a.y = r0.y * ev; a.z = r0.z * ev; a.w = r0.w * ev;
    auto addf4 = [&](const float4& v) {
        a.x += v.x; a.y += v.y; a.z += v.z; a.w += v.w;
    };
    int e = 0;
    for (; e + 4 <= deg; e += 4) {
        if (e + 3 < deg) r0 = X[(size_t)colv[e0 + e + 3] * 256 + tid];
        addf4(r1);
        if (e + 4 < deg) r1 = X[(size_t)colv[e0 + e + 4] * 256 + tid];
        addf4(r2);
        if (e + 5 < deg) r2 = X[(size_t)colv[e0 + e + 5] * 256 + tid];
        addf4(r3);
        if (e + 6 < deg) r3 = X[(size_t)colv[e0 + e + 6] * 256 + tid];
        addf4(r0);
    }
    int rem = deg - e;
    if (rem > 0) addf4(r1);
    if (rem > 1) addf4(r2);
    if (rem > 2) addf4(r3);

    {
        int m = tid >> 2, k0 = (tid & 3) * 4;
        int addr = ((k0 >> 3) * 64 + m) * 8 + (k0 & 7);
        uint2 pv;
        pv.x = f2bf(a.x) | ((unsigned)f2bf(a.y) << 16);
        pv.y = f2bf(a.z) | ((unsigned)f2bf(a.w) << 16);
        *(uint2*)&Zs[addr] = pv;
        *(uint2*)&Zs[1024 + tid * 4] = make_uint2(0u, 0u);
    }
    __syncthreads();

    int w = tid >> 6, lane = tid & 63, lg = lane >> 4, ln = lane & 15;
    floatx4 C[4][2];
#pragma unroll
    for (int mt = 0; mt < 4; mt++) { C[mt][0] = {0.f, 0.f, 0.f, 0.f}; C[mt][1] = {0.f, 0.f, 0.f, 0.f}; }

    {
        short8 B0 = *(const short8*)&W1t[(w * 32 + ln) * 32 + lg * 8];
        short8 B1 = *(const short8*)&W1t[(w * 32 + 16 + ln) * 32 + lg * 8];
#pragma unroll
        for (int mt = 0; mt < 4; mt++) {
            short8 A = *(const short8*)&Zs[(lg * 64 + mt * 16 + ln) * 8];
            C[mt][0] = __builtin_amdgcn_mfma_f32_16x16x32_bf16(A, B0, C[mt][0], 0, 0, 0);
            C[mt][1] = __builtin_amdgcn_mfma_f32_16x16x32_bf16(A, B1, C[mt][1], 0, 0, 0);
        }
    }

    float bsum[2], bsq[2];
    float bv[2] = {b1[w * 32 + ln], b1[w * 32 + 16 + ln]};
#pragma unroll
    for (int nt = 0; nt < 2; nt++) {
        float s = 0.f, s2 = 0.f;
#pragma unroll
        for (int mt = 0; mt < 4; mt++)
#pragma unroll
            for (int r = 0; r < 4; r++) {
                float v = C[mt][nt][r] + bv[nt];
                C[mt][nt][r] = v;
                s += v; s2 += v * v;
            }
        bsum[nt] = s; bsq[nt] = s2;
    }
#pragma unroll
    for (int nt = 0; nt < 2; nt++) {
        bsum[nt] += __shfl_xor(bsum[nt], 16, 64);
        bsum[nt] += __shfl_xor(bsum[nt], 32, 64);
        bsq[nt] += __shfl_xor(bsq[nt], 16, 64);
        bsq[nt] += __shfl_xor(bsq[nt], 32, 64);
    }
    if (lg == 0) {
        int c0 = w * 32 + ln;
        atomicAdd(&sums[c0], bsum[0]);
        atomicAdd(&sums[c0 + 16], bsum[1]);
        atomicAdd(&sums[128 + c0], bsq[0]);
        atomicAdd(&sums[128 + c0 + 16], bsq[1]);
    }
    __syncthreads();
#pragma unroll
    for (int nt = 0; nt < 2; nt++) {
        int colc = w * 32 + nt * 16 + ln;
        int base = (colc >> 3) * 512 + (colc & 7);
#pragma unroll
        for (int mt = 0; mt < 4; mt++)
#pragma unroll
            for (int r = 0; r < 4; r++) {
                int row = mt * 16 + lg * 4 + r;
                Zs[base + row * 8] = f2bf(C[mt][nt][r]);
            }
    }
    __syncthreads();
#pragma unroll
    for (int q = 0; q < 4; q++)
        nt_store16(&((const uint4*)Zs)[q * 256 + tid], &((uint4*)&H[(size_t)n * 8192])[q * 256 + tid]);
}

// ---------------- fused layers 1..3 (512 threads, pk-f32 math, 4-deep ring) ----------------
// Computes scale/shift from previous layer's atomic sums per block, gathers
// relu(bn(Hin)), matmul by W21 = W2[l-1]@W1[l], bias = b1 + (1+eps+deg)*bvec;
// accumulates this layer's BN sums via atomicAdd.
__global__ __launch_bounds__(512, 4) void gin_mm1_fused(const ushort_t* __restrict__ Hin,
                                                        const ushort_t* __restrict__ W21t,
                                                        const float* __restrict__ b1, const float* __restrict__ bvec,
                                                        const float* __restrict__ sums_prev,
                                                        const float* __restrict__ gam_prev,
                                                        const float* __restrict__ bet_prev,
                                                        const float* __restrict__ epsp,
                                                        const int* __restrict__ rp, const int* __restrict__ colv,
                                                        ushort_t* __restrict__ Hout, float* __restrict__ sums_cur) {
    __shared__ ushort_t Zs[64 * 128];   // 16 KB
    __shared__ float scs_lds[256];      // 1 KB
    int tid = threadIdx.x, n = blockIdx.x;
    if (tid < 128) {
        float mean = sums_prev[tid] * (1.f / (float)ROWS);
        float var = sums_prev[128 + tid] * (1.f / (float)ROWS) - mean * mean;
        float sc = gam_prev[tid] * rsqrtf(var + 1e-5f);
        scs_lds[tid] = sc;
        scs_lds[128 + tid] = bet_prev[tid] - mean * sc;
    }
    __syncthreads();

    // hoisted BN constants for this thread's 2 uint4 chunks (chunk q at index q*512+tid)
    float2v sc2[2][4], sh2[2][4];
#pragma unroll
    for (int q = 0; q < 2; q++) {
        int cb = ((q * 512 + tid) >> 6) * 8;
#pragma unroll
        for (int i = 0; i < 4; i++) {
            sc2[q][i].x = scs_lds[cb + 2 * i];     sc2[q][i].y = scs_lds[cb + 2 * i + 1];
            sh2[q][i].x = scs_lds[128 + cb + 2 * i]; sh2[q][i].y = scs_lds[128 + cb + 2 * i + 1];
        }
    }

    float ev = 1.0f + epsp[0];
    int e0 = rp[n], e1 = rp[n + 1], deg = e1 - e0;
    const uint4* X = (const uint4*)Hin;
    const float2v zero2 = {0.f, 0.f};

    uint4 r0[2], r1[2], r2[2], r3[2];
    auto ld = [&](uint4* buf, int node) {
        const uint4* p = X + (size_t)node * 1024;
        buf[0] = p[tid];
        buf[1] = p[512 + tid];
    };
    ld(r0, n);
    if (deg > 0) ld(r1, colv[e0]);
    if (deg > 1) ld(r2, colv[e0 + 1]);
    if (deg > 2) ld(r3, colv[e0 + 2]);

    float2v acc[2][4];
#pragma unroll
    for (int q = 0; q < 2; q++) {
        unsigned u[4] = {r0[q].x, r0[q].y, r0[q].z, r0[q].w};
#pragma unroll
        for (int i = 0; i < 4; i++) {
            float2v t = __builtin_elementwise_fma(bfpair(u[i]), sc2[q][i], sh2[q][i]);
            acc[q][i] = __builtin_elementwise_max(t, zero2) * ev;
        }
    }
    auto addp = [&](const uint4* buf) {
#pragma unroll
        for (int q = 0; q < 2; q++) {
            unsigned u[4] = {buf[q].x, buf[q].y, buf[q].z, buf[q].w};
#pragma unroll
            for (int i = 0; i < 4; i++) {
                float2v t = __builtin_elementwise_fma(bfpair(u[i]), sc2[q][i], sh2[q][i]);
                acc[q][i] += __builtin_elementwise_max(t, zero2);
            }
        }
    };

    int e = 0;
    for (; e + 4 <= deg; e += 4) {
        if (e + 3 < deg) ld(r0, colv[e0 + e + 3]);
        addp(r1);
        if (e + 4 < deg) ld(r1, colv[e0 + e + 4]);
        addp(r2);
        if (e + 5 < deg) ld(r2, colv[e0 + e + 5]);
        addp(r3);
        if (e + 6 < deg) ld(r3, colv[e0 + e + 6]);
        addp(r0);
    }
    int rem = deg - e;
    if (rem > 0) addp(r1);
    if (rem > 1) addp(r2);
    if (rem > 2) addp(r3);

#pragma unroll
    for (int q = 0; q < 2; q++) {
        uint4 pv;
        pv.x = f2bf(acc[q][0].x) | ((unsigned)f2bf(acc[q][0].y) << 16);
        pv.y = f2bf(acc[q][1].x) | ((unsigned)f2bf(acc[q][1].y) << 16);
        pv.z = f2bf(acc[q][2].x) | ((unsigned)f2bf(acc[q][2].y) << 16);
        pv.w = f2bf(acc[q][3].x) | ((unsigned)f2bf(acc[q][3].y) << 16);
        ((uint4*)Zs)[q * 512 + tid] = pv;
    }
    __syncthreads();

    // MFMA: 8 waves, each owns 16 output cols, all 64 rows (4 M-tiles)
    int w = tid >> 6, lane = tid & 63, lg = lane >> 4, ln = lane & 15;
    floatx4 C[4];
#pragma unroll
    for (int mt = 0; mt < 4; mt++) C[mt] = {0.f, 0.f, 0.f, 0.f};

    for (int kb = 0; kb < 4; kb++) {
        short8 B = *(const short8*)&W21t[(w * 16 + ln) * 128 + kb * 32 + lg * 8];
#pragma unroll
        for (int mt = 0; mt < 4; mt++) {
            short8 A = *(const short8*)&Zs[((kb * 4 + lg) * 64 + mt * 16 + ln) * 8];
            C[mt] = __builtin_amdgcn_mfma_f32_16x16x32_bf16(A, B, C[mt], 0, 0, 0);
        }
    }

    float fac = ev + (float)deg;
    int c0 = w * 16 + ln;
    float bv = b1[c0] + fac * bvec[c0];
    float s = 0.f, s2 = 0.f;
#pragma unroll
    for (int mt = 0; mt < 4; mt++)
#pragma unroll
        for (int r = 0; r < 4; r++) {
            float v = C[mt][r] + bv;
            C[mt][r] = v;
            s += v; s2 += v * v;
        }
    s += __shfl_xor(s, 16, 64);
    s += __shfl_xor(s, 32, 64);
    s2 += __shfl_xor(s2, 16, 64);
    s2 += __shfl_xor(s2, 32, 64);
    if (lg == 0) {
        atomicAdd(&sums_cur[c0], s);
        atomicAdd(&sums_cur[128 + c0], s2);
    }

    __syncthreads();
    {
        int base = (c0 >> 3) * 512 + (c0 & 7);
#pragma unroll
        for (int mt = 0; mt < 4; mt++)
#pragma unroll
            for (int r = 0; r < 4; r++) {
                int row = mt * 16 + lg * 4 + r;
                Zs[base + row * 8] = f2bf(C[mt][r]);
            }
    }
    __syncthreads();
#pragma unroll
    for (int q = 0; q < 2; q++)
        nt_store16(&((const uint4*)Zs)[q * 512 + tid], &((uint4*)&Hout[(size_t)n * 8192])[q * 512 + tid]);
}

// ---------------- final: PE = sum_rows mask * (relu(bn(H3)) @ W2l + b2l) ----------------
__global__ __launch_bounds__(256, 4) void gin_mm2_last(const ushort_t* __restrict__ H, const ushort_t* __restrict__ W2t,
                                                       const float* __restrict__ b2,
                                                       const float* __restrict__ sums_prev,
                                                       const float* __restrict__ gam_prev,
                                                       const float* __restrict__ bet_prev,
                                                       const float* __restrict__ mask, float* __restrict__ out) {
    __shared__ ushort_t Hs[64 * 128];
    __shared__ float scs_lds[256];
    int tid = threadIdx.x, n = blockIdx.x;
    if (tid < 128) {
        float mean = sums_prev[tid] * (1.f / (float)ROWS);
        float var = sums_prev[128 + tid] * (1.f / (float)ROWS) - mean * mean;
        float sc = gam_prev[tid] * rsqrtf(var + 1e-5f);
        scs_lds[tid] = sc;
        scs_lds[128 + tid] = bet_prev[tid] - mean * sc;
    }
    __syncthreads();

#pragma unroll
    for (int q = 0; q < 4; q++) {
        int c = q * 256 + tid;
        uint4 v = ((const uint4*)&H[(size_t)n * 8192])[c];
        float f[8]; unpack8(v, f);
        int cb = (c >> 6) * 8;
#pragma unroll
        for (int j = 0; j < 8; j++) f[j] = fmaxf(fmaf(f[j], scs_lds[cb + j], scs_lds[128 + cb + j]), 0.f);
        ((uint4*)Hs)[c] = pack8(f);
    }
    __syncthreads();

    int w = tid >> 6, lane = tid & 63, lg = lane >> 4, ln = lane & 15;
    floatx4 C[4];
#pragma unroll
    for (int mt = 0; mt < 4; mt++) C[mt] = {0.f, 0.f, 0.f, 0.f};

    for (int kb = 0; kb < 4; kb++) {
        short8 B = *(const short8*)&W2t[(w * 16 + ln) * 128 + kb * 32 + lg * 8];
#pragma unroll
        for (int mt = 0; mt < 4; mt++) {
            short8 A = *(const short8*)&Hs[((kb * 4 + lg) * 64 + mt * 16 + ln) * 8];
            C[mt] = __builtin_amdgcn_mfma_f32_16x16x32_bf16(A, B, C[mt], 0, 0, 0);
        }
    }

    int colc = w * 16 + ln;
    float bb = b2[colc];
    float pe = 0.f;
#pragma unroll
    for (int mt = 0; mt < 4; mt++)
#pragma unroll
        for (int r = 0; r < 4; r++) {
            int row = mt * 16 + lg * 4 + r;
            pe += mask[n * 64 + row] * (C[mt][r] + bb);
        }
    pe += __shfl_xor(pe, 16, 64);
    pe += __shfl_xor(pe, 32, 64);
    if (lg == 0) out[(size_t)n * 64 + colc] = pe;
}

// ---------------- host launch ----------------
extern "C" void kernel_launch(void* const* d_in, const int* in_sizes, int n_in, void* d_out, int out_size,
                              void* d_ws, size_t ws_size, hipStream_t stream) {
    const float* W    = (const float*)d_in[0];
    const float* mask = (const float*)d_in[1];
    const int* src    = (const int*)d_in[2];
    const int* dst    = (const int*)d_in[3];
    const float* eps  = (const float*)d_in[4];
    const float* W1f  = (const float*)d_in[5];
    const float* b1f  = (const float*)d_in[6];
    const float* W1r  = (const float*)d_in[7];
    const float* b1r  = (const float*)d_in[8];
    const float* gam  = (const float*)d_in[9];
    const float* bet  = (const float*)d_in[10];
    const float* W2m  = (const float*)d_in[11];
    const float* b2m  = (const float*)d_in[12];
    const float* W2l  = (const float*)d_in[13];
    const float* b2l  = (const float*)d_in[14];
    float* out = (float*)d_out;

    // workspace layout
    ushort_t* Ha   = (ushort_t*)d_ws;          // 16,777,216
    ushort_t* Hb   = Ha + 16777216;            // 16,777,216
    ushort_t* w1t0 = Hb + 16777216;            // 4096
    ushort_t* w2lt = w1t0 + 4096;              // 8192
    ushort_t* w21t = w2lt + 8192;              // 49152
    float* bvec    = (float*)(w21t + 49152);   // 384
    int* ideg      = (int*)(bvec + 384);       // 2048
    int* icur      = ideg + 2048;              // 2048
    float* sums    = (float*)(icur + 2048);    // 1024 (4 layers x 256) -- zeroed with ideg/icur
    int* irp       = (int*)(sums + 1024);      // 2049
    int* icol      = irp + 2052;               // 16384

    // zero deg/cursor/sums in one kernel (contiguous 5120 words)
    zero_ints<<<20, 256, 0, stream>>>(ideg, 5120);
    count_deg<<<NEDGE / 256, 256, 0, stream>>>(dst, ideg);
    scan_deg<<<1, 256, 0, stream>>>(ideg, irp);
    fill_csr<<<NEDGE / 256, 256, 0, stream>>>(src, dst, irp, icur, icol);
    prep_small<<<50, 256, 0, stream>>>(W1f, W2l, b2m, W1r, w1t0, w2lt, bvec);
    prep_w21<<<192, 256, 0, stream>>>(W2m, W1r, w21t);

    // layer 0 (stats -> sums[0])
    gin_mm1_l0<<<N_SUM, 256, 0, stream>>>(W, w1t0, b1f, eps, irp, icol, Ha, sums);
    // layers 1..3 (consume sums[l-1], produce sums[l])
    gin_mm1_fused<<<N_SUM, 512, 0, stream>>>(Ha, w21t, b1r, bvec, sums, gam, bet, eps + 1,
                                             irp, icol, Hb, sums + 256);
    gin_mm1_fused<<<N_SUM, 512, 0, stream>>>(Hb, w21t + 16384, b1r + 128, bvec + 128, sums + 256,
                                             gam + 128, bet + 128, eps + 2, irp, icol, Ha, sums + 512);
    gin_mm1_fused<<<N_SUM, 512, 0, stream>>>(Ha, w21t + 32768, b1r + 256, bvec + 256, sums + 512,
                                             gam + 256, bet + 256, eps + 3, irp, icol, Hb, sums + 768);
    // final (consumes sums[3])
    gin_mm2_last<<<N_SUM, 256, 0, stream>>>(Hb, w2lt, b2l, sums + 768, gam + 384, bet + 384, mask, out);
}

// Round 7
// 374.681 us; speedup vs baseline: 1.0044x; 1.0044x over previous
//
#include <hip/hip_runtime.h>

#define N_SUM 2048
#define HIDD 128
#define NEDGE 16384
#define ROWS (N_SUM * 64)

typedef short short8 __attribute__((ext_vector_type(8)));
typedef float floatx4 __attribute__((ext_vector_type(4)));
typedef float float2v __attribute__((ext_vector_type(2)));
typedef unsigned int uint4n __attribute__((ext_vector_type(4)));
typedef unsigned short ushort_t;

__device__ __forceinline__ ushort_t f2bf(float f) {
    unsigned u = __builtin_bit_cast(unsigned, f);
    u += 0x7fffu + ((u >> 16) & 1u);   // RNE
    return (ushort_t)(u >> 16);
}
__device__ __forceinline__ float bf2f(ushort_t h) {
    return __builtin_bit_cast(float, (unsigned)h << 16);
}
// uint32 holding two bf16 -> float2 (elem0 = low half, elem1 = high half)
__device__ __forceinline__ float2v bfpair(unsigned u) {
    float2v r;
    r.x = __builtin_bit_cast(float, u << 16);
    r.y = __builtin_bit_cast(float, u & 0xffff0000u);
    return r;
}
__device__ __forceinline__ void unpack8(uint4 v, float* f) {
    f[0] = bf2f(v.x & 0xffff); f[1] = bf2f(v.x >> 16);
    f[2] = bf2f(v.y & 0xffff); f[3] = bf2f(v.y >> 16);
    f[4] = bf2f(v.z & 0xffff); f[5] = bf2f(v.z >> 16);
    f[6] = bf2f(v.w & 0xffff); f[7] = bf2f(v.w >> 16);
}
__device__ __forceinline__ uint4 pack8(const float* f) {
    uint4 v;
    v.x = f2bf(f[0]) | ((unsigned)f2bf(f[1]) << 16);
    v.y = f2bf(f[2]) | ((unsigned)f2bf(f[3]) << 16);
    v.z = f2bf(f[4]) | ((unsigned)f2bf(f[5]) << 16);
    v.w = f2bf(f[6]) | ((unsigned)f2bf(f[7]) << 16);
    return v;
}
__device__ __forceinline__ void nt_store16(const void* src, void* dst) {
    __builtin_nontemporal_store(*(const uint4n*)src, (uint4n*)dst);
}

// ---------------- CSR build ----------------
__global__ __launch_bounds__(256) void zero_ints(int* p, int n) {
    int i = blockIdx.x * 256 + threadIdx.x;
    if (i < n) p[i] = 0;
}

__global__ __launch_bounds__(256) void count_deg(const int* __restrict__ dst, int* __restrict__ deg) {
    int e = blockIdx.x * 256 + threadIdx.x;
    if (e < NEDGE) atomicAdd(&deg[dst[e]], 1);
}

__global__ __launch_bounds__(256) void scan_deg(const int* __restrict__ deg, int* __restrict__ row_ptr) {
    __shared__ int csum[256];
    int t = threadIdx.x;
    int loc[8];
    int s = 0;
#pragma unroll
    for (int q = 0; q < 8; q++) { loc[q] = s; s += deg[t * 8 + q]; }
    csum[t] = s;
    __syncthreads();
    for (int off = 1; off < 256; off <<= 1) {
        int v = (t >= off) ? csum[t - off] : 0;
        __syncthreads();
        csum[t] += v;
        __syncthreads();
    }
    int base = (t == 0) ? 0 : csum[t - 1];
#pragma unroll
    for (int q = 0; q < 8; q++) row_ptr[t * 8 + q] = base + loc[q];
    if (t == 255) row_ptr[2048] = csum[255];
}

__global__ __launch_bounds__(256) void fill_csr(const int* __restrict__ src, const int* __restrict__ dst,
                                                const int* __restrict__ row_ptr, int* __restrict__ cursor,
                                                int* __restrict__ col) {
    int e = blockIdx.x * 256 + threadIdx.x;
    if (e < NEDGE) {
        int d = dst[e];
        int pos = atomicAdd(&cursor[d], 1);
        col[row_ptr[d] + pos] = src[e];
    }
}

// ---------------- weight prep ----------------
__global__ __launch_bounds__(256) void prep_small(const float* __restrict__ W1f, const float* __restrict__ W2l,
                                                  const float* __restrict__ b2m, const float* __restrict__ W1r,
                                                  ushort_t* __restrict__ w1t0, ushort_t* __restrict__ w2lt,
                                                  float* __restrict__ bvec) {
    int idx = blockIdx.x * 256 + threadIdx.x;
    if (idx < 4096) {
        int nn = idx >> 5, k = idx & 31;
        w1t0[idx] = f2bf(k < 16 ? W1f[k * 128 + nn] : 0.f);
    } else if (idx < 4096 + 8192) {
        int r = idx - 4096;
        int nn = r >> 7, k = r & 127;
        w2lt[r] = f2bf(W2l[k * 64 + nn]);
    } else if (idx < 4096 + 8192 + 384) {
        int r = idx - 12288;
        int lm = r >> 7, c = r & 127;
        float s = 0.f;
        for (int o = 0; o < 128; o++) s += b2m[lm * 128 + o] * W1r[(size_t)lm * 16384 + o * 128 + c];
        bvec[r] = s;
    }
}

// w21t[lm][c][i] = bf16( sum_o W2m[lm][i][o] * W1r[lm][o][c] )  -- B-fragment layout [n=c][k=i]
__global__ __launch_bounds__(256) void prep_w21(const float* __restrict__ W2m, const float* __restrict__ W1r,
                                                ushort_t* __restrict__ w21t) {
    int idx = blockIdx.x * 256 + threadIdx.x;  // 49152 total
    int lm = idx >> 14, r = idx & 16383, i = r >> 7, c = r & 127;
    const float* w2row = W2m + (size_t)lm * 16384 + i * 128;
    const float* w1col = W1r + (size_t)lm * 16384 + c;
    float s = 0.f;
#pragma unroll 8
    for (int o = 0; o < 128; o++) s += w2row[o] * w1col[o * 128];
    w21t[(size_t)lm * 16384 + c * 128 + i] = f2bf(s);
}

// A-layout for a 64x128 (or 64x32) bf16 tile: elem(m, k) at ((k>>3)*64 + m)*8 + (k&7)

// ---------------- layer 0: gather fp32 W + MFMA (K=16 padded to 32) ----------------
// 2-deep branch-free pipelined gather (round-5 structure); BN stats via atomicAdd.
__global__ __launch_bounds__(256, 4) void gin_mm1_l0(const float* __restrict__ Xf, const ushort_t* __restrict__ W1t,
                                                     const float* __restrict__ b1, const float* __restrict__ eps,
                                                     const int* __restrict__ rp, const int* __restrict__ colv,
                                                     ushort_t* __restrict__ H, float* __restrict__ sums) {
    __shared__ ushort_t Zs[64 * 128];  // 16 KB
    int tid = threadIdx.x, n = blockIdx.x;
    float ev = 1.0f + eps[0];
    int e0 = rp[n], e1 = rp[n + 1], deg = e1 - e0;
    const float4* X = (const float4*)Xf;

    float4 sA, sB;
    sA = X[(size_t)n * 256 + tid];
    if (deg > 0) sB = X[(size_t)colv[e0] * 256 + tid];
    float4 a;
    a.x = sA.x * ev; a.y = sA.y * ev; a.z = sA.z * ev; a.w = sA.w * ev;
    int i = 1;
    for (; i + 1 < deg; i += 2) {
        sA = X[(size_t)colv[e0 + i] * 256 + tid];
        a.x += sB.x; a.y += sB.y; a.z += sB.z; a.w += sB.w;
        sB = X[(size_t)colv[e0 + i + 1] * 256 + tid];
        a.x += sA.x; a.y += sA.y; a.z += sA.z; a.w += sA.w;
    }
    if (deg > 0) {
        if (i < deg) {
            sA = X[(size_t)colv[e0 + i] * 256 + tid];
            a.x += sB.x; a.y += sB.y; a.z += sB.z; a.w += sB.w;
            a.x += sA.x; a.y += sA.y; a.z += sA.z; a.w += sA.w;
        } else {
            a.x += sB.x; a.y += sB.y; a.z += sB.z; a.w += sB.w;
        }
    }

    {
        int m = tid >> 2, k0 = (tid & 3) * 4;
        int addr = ((k0 >> 3) * 64 + m) * 8 + (k0 & 7);
        uint2 pv;
        pv.x = f2bf(a.x) | ((unsigned)f2bf(a.y) << 16);
        pv.y = f2bf(a.z) | ((unsigned)f2bf(a.w) << 16);
        *(uint2*)&Zs[addr] = pv;
        *(uint2*)&Zs[1024 + tid * 4] = make_uint2(0u, 0u);
    }
    __syncthreads();

    int w = tid >> 6, lane = tid & 63, lg = lane >> 4, ln = lane & 15;
    floatx4 C[4][2];
#pragma unroll
    for (int mt = 0; mt < 4; mt++) { C[mt][0] = {0.f, 0.f, 0.f, 0.f}; C[mt][1] = {0.f, 0.f, 0.f, 0.f}; }

    {
        short8 B0 = *(const short8*)&W1t[(w * 32 + ln) * 32 + lg * 8];
        short8 B1 = *(const short8*)&W1t[(w * 32 + 16 + ln) * 32 + lg * 8];
#pragma unroll
        for (int mt = 0; mt < 4; mt++) {
            short8 A = *(const short8*)&Zs[(lg * 64 + mt * 16 + ln) * 8];
            C[mt][0] = __builtin_amdgcn_mfma_f32_16x16x32_bf16(A, B0, C[mt][0], 0, 0, 0);
            C[mt][1] = __builtin_amdgcn_mfma_f32_16x16x32_bf16(A, B1, C[mt][1], 0, 0, 0);
        }
    }

    float bsum[2], bsq[2];
    float bv[2] = {b1[w * 32 + ln], b1[w * 32 + 16 + ln]};
#pragma unroll
    for (int nt = 0; nt < 2; nt++) {
        float s = 0.f, s2 = 0.f;
#pragma unroll
        for (int mt = 0; mt < 4; mt++)
#pragma unroll
            for (int r = 0; r < 4; r++) {
                float v = C[mt][nt][r] + bv[nt];
                C[mt][nt][r] = v;
                s += v; s2 += v * v;
            }
        bsum[nt] = s; bsq[nt] = s2;
    }
#pragma unroll
    for (int nt = 0; nt < 2; nt++) {
        bsum[nt] += __shfl_xor(bsum[nt], 16, 64);
        bsum[nt] += __shfl_xor(bsum[nt], 32, 64);
        bsq[nt] += __shfl_xor(bsq[nt], 16, 64);
        bsq[nt] += __shfl_xor(bsq[nt], 32, 64);
    }
    if (lg == 0) {
        int c0 = w * 32 + ln;
        atomicAdd(&sums[c0], bsum[0]);
        atomicAdd(&sums[c0 + 16], bsum[1]);
        atomicAdd(&sums[128 + c0], bsq[0]);
        atomicAdd(&sums[128 + c0 + 16], bsq[1]);
    }
    __syncthreads();
#pragma unroll
    for (int nt = 0; nt < 2; nt++) {
        int colc = w * 32 + nt * 16 + ln;
        int base = (colc >> 3) * 512 + (colc & 7);
#pragma unroll
        for (int mt = 0; mt < 4; mt++)
#pragma unroll
            for (int r = 0; r < 4; r++) {
                int row = mt * 16 + lg * 4 + r;
                Zs[base + row * 8] = f2bf(C[mt][nt][r]);
            }
    }
    __syncthreads();
#pragma unroll
    for (int q = 0; q < 4; q++)
        nt_store16(&((const uint4*)Zs)[q * 256 + tid], &((uint4*)&H[(size_t)n * 8192])[q * 256 + tid]);
}

// ---------------- fused layers 1..3 (512 threads, 2-deep branch-free pipeline, pk-f32) ----------------
// Computes scale/shift from previous layer's atomic sums per block, gathers
// relu(bn(Hin)), matmul by W21 = W2[l-1]@W1[l], bias = b1 + (1+eps+deg)*bvec;
// accumulates this layer's BN sums via atomicAdd.
__global__ __launch_bounds__(512, 4) void gin_mm1_fused(const ushort_t* __restrict__ Hin,
                                                        const ushort_t* __restrict__ W21t,
                                                        const float* __restrict__ b1, const float* __restrict__ bvec,
                                                        const float* __restrict__ sums_prev,
                                                        const float* __restrict__ gam_prev,
                                                        const float* __restrict__ bet_prev,
                                                        const float* __restrict__ epsp,
                                                        const int* __restrict__ rp, const int* __restrict__ colv,
                                                        ushort_t* __restrict__ Hout, float* __restrict__ sums_cur) {
    __shared__ ushort_t Zs[64 * 128];   // 16 KB
    __shared__ float scs_lds[256];      // 1 KB
    int tid = threadIdx.x, n = blockIdx.x;
    if (tid < 128) {
        float mean = sums_prev[tid] * (1.f / (float)ROWS);
        float var = sums_prev[128 + tid] * (1.f / (float)ROWS) - mean * mean;
        float sc = gam_prev[tid] * rsqrtf(var + 1e-5f);
        scs_lds[tid] = sc;
        scs_lds[128 + tid] = bet_prev[tid] - mean * sc;
    }
    __syncthreads();

    // hoisted BN constants for this thread's 2 uint4 chunks (chunk q at index q*512+tid)
    float2v sc2[2][4], sh2[2][4];
#pragma unroll
    for (int q = 0; q < 2; q++) {
        int cb = ((q * 512 + tid) >> 6) * 8;
#pragma unroll
        for (int i = 0; i < 4; i++) {
            sc2[q][i].x = scs_lds[cb + 2 * i];       sc2[q][i].y = scs_lds[cb + 2 * i + 1];
            sh2[q][i].x = scs_lds[128 + cb + 2 * i]; sh2[q][i].y = scs_lds[128 + cb + 2 * i + 1];
        }
    }

    float ev = 1.0f + epsp[0];
    int e0 = rp[n], e1 = rp[n + 1], deg = e1 - e0;
    const uint4* X = (const uint4*)Hin;
    const float2v zero2 = {0.f, 0.f};

    float2v acc[2][4];
    uint4 bufA[2], bufB[2];
    auto loadslab = [&](uint4* buf, int node) {
        const uint4* p = X + (size_t)node * 1024;
        buf[0] = p[tid];
        buf[1] = p[512 + tid];
    };
    auto addp = [&](const uint4* buf) {
#pragma unroll
        for (int q = 0; q < 2; q++) {
            unsigned u[4] = {buf[q].x, buf[q].y, buf[q].z, buf[q].w};
#pragma unroll
            for (int i = 0; i < 4; i++) {
                float2v t = __builtin_elementwise_fma(bfpair(u[i]), sc2[q][i], sh2[q][i]);
                acc[q][i] += __builtin_elementwise_max(t, zero2);
            }
        }
    };

    loadslab(bufA, n);
    if (deg > 0) loadslab(bufB, colv[e0]);

    // self: acc = ev * relu(x*sc + sh)
#pragma unroll
    for (int q = 0; q < 2; q++) {
        unsigned u[4] = {bufA[q].x, bufA[q].y, bufA[q].z, bufA[q].w};
#pragma unroll
        for (int i = 0; i < 4; i++) {
            float2v t = __builtin_elementwise_fma(bfpair(u[i]), sc2[q][i], sh2[q][i]);
            acc[q][i] = __builtin_elementwise_max(t, zero2) * ev;
        }
    }

    int i = 1;
    for (; i + 1 < deg; i += 2) {
        loadslab(bufA, colv[e0 + i]);
        addp(bufB);
        loadslab(bufB, colv[e0 + i + 1]);
        addp(bufA);
    }
    if (deg > 0) {
        if (i < deg) {
            loadslab(bufA, colv[e0 + i]);
            addp(bufB);
            addp(bufA);
        } else {
            addp(bufB);
        }
    }

#pragma unroll
    for (int q = 0; q < 2; q++) {
        uint4 pv;
        pv.x = f2bf(acc[q][0].x) | ((unsigned)f2bf(acc[q][0].y) << 16);
        pv.y = f2bf(acc[q][1].x) | ((unsigned)f2bf(acc[q][1].y) << 16);
        pv.z = f2bf(acc[q][2].x) | ((unsigned)f2bf(acc[q][2].y) << 16);
        pv.w = f2bf(acc[q][3].x) | ((unsigned)f2bf(acc[q][3].y) << 16);
        ((uint4*)Zs)[q * 512 + tid] = pv;
    }
    __syncthreads();

    // MFMA: 8 waves, each owns 16 output cols, all 64 rows (4 M-tiles)
    int w = tid >> 6, lane = tid & 63, lg = lane >> 4, ln = lane & 15;
    floatx4 C[4];
#pragma unroll
    for (int mt = 0; mt < 4; mt++) C[mt] = {0.f, 0.f, 0.f, 0.f};

    for (int kb = 0; kb < 4; kb++) {
        short8 B = *(const short8*)&W21t[(w * 16 + ln) * 128 + kb * 32 + lg * 8];
#pragma unroll
        for (int mt = 0; mt < 4; mt++) {
            short8 A = *(const short8*)&Zs[((kb * 4 + lg) * 64 + mt * 16 + ln) * 8];
            C[mt] = __builtin_amdgcn_mfma_f32_16x16x32_bf16(A, B, C[mt], 0, 0, 0);
        }
    }

    float fac = ev + (float)deg;
    int c0 = w * 16 + ln;
    float bv = b1[c0] + fac * bvec[c0];
    float s = 0.f, s2 = 0.f;
#pragma unroll
    for (int mt = 0; mt < 4; mt++)
#pragma unroll
        for (int r = 0; r < 4; r++) {
            float v = C[mt][r] + bv;
            C[mt][r] = v;
            s += v; s2 += v * v;
        }
    s += __shfl_xor(s, 16, 64);
    s += __shfl_xor(s, 32, 64);
    s2 += __shfl_xor(s2, 16, 64);
    s2 += __shfl_xor(s2, 32, 64);
    if (lg == 0) {
        atomicAdd(&sums_cur[c0], s);
        atomicAdd(&sums_cur[128 + c0], s2);
    }

    __syncthreads();
    {
        int base = (c0 >> 3) * 512 + (c0 & 7);
#pragma unroll
        for (int mt = 0; mt < 4; mt++)
#pragma unroll
            for (int r = 0; r < 4; r++) {
                int row = mt * 16 + lg * 4 + r;
                Zs[base + row * 8] = f2bf(C[mt][r]);
            }
    }
    __syncthreads();
#pragma unroll
    for (int q = 0; q < 2; q++)
        nt_store16(&((const uint4*)Zs)[q * 512 + tid], &((uint4*)&Hout[(size_t)n * 8192])[q * 512 + tid]);
}

// ---------------- final: PE = sum_rows mask * (relu(bn(H3)) @ W2l + b2l) ----------------
__global__ __launch_bounds__(256, 4) void gin_mm2_last(const ushort_t* __restrict__ H, const ushort_t* __restrict__ W2t,
                                                       const float* __restrict__ b2,
                                                       const float* __restrict__ sums_prev,
                                                       const float* __restrict__ gam_prev,
                                                       const float* __restrict__ bet_prev,
                                                       const float* __restrict__ mask, float* __restrict__ out) {
    __shared__ ushort_t Hs[64 * 128];
    __shared__ float scs_lds[256];
    int tid = threadIdx.x, n = blockIdx.x;
    if (tid < 128) {
        float mean = sums_prev[tid] * (1.f / (float)ROWS);
        float var = sums_prev[128 + tid] * (1.f / (float)ROWS) - mean * mean;
        float sc = gam_prev[tid] * rsqrtf(var + 1e-5f);
        scs_lds[tid] = sc;
        scs_lds[128 + tid] = bet_prev[tid] - mean * sc;
    }
    __syncthreads();

#pragma unroll
    for (int q = 0; q < 4; q++) {
        int c = q * 256 + tid;
        uint4 v = ((const uint4*)&H[(size_t)n * 8192])[c];
        float f[8]; unpack8(v, f);
        int cb = (c >> 6) * 8;
#pragma unroll
        for (int j = 0; j < 8; j++) f[j] = fmaxf(fmaf(f[j], scs_lds[cb + j], scs_lds[128 + cb + j]), 0.f);
        ((uint4*)Hs)[c] = pack8(f);
    }
    __syncthreads();

    int w = tid >> 6, lane = tid & 63, lg = lane >> 4, ln = lane & 15;
    floatx4 C[4];
#pragma unroll
    for (int mt = 0; mt < 4; mt++) C[mt] = {0.f, 0.f, 0.f, 0.f};

    for (int kb = 0; kb < 4; kb++) {
        short8 B = *(const short8*)&W2t[(w * 16 + ln) * 128 + kb * 32 + lg * 8];
#pragma unroll
        for (int mt = 0; mt < 4; mt++) {
            short8 A = *(const short8*)&Hs[((kb * 4 + lg) * 64 + mt * 16 + ln) * 8];
            C[mt] = __builtin_amdgcn_mfma_f32_16x16x32_bf16(A, B, C[mt], 0, 0, 0);
        }
    }

    int colc = w * 16 + ln;
    float bb = b2[colc];
    float pe = 0.f;
#pragma unroll
    for (int mt = 0; mt < 4; mt++)
#pragma unroll
        for (int r = 0; r < 4; r++) {
            int row = mt * 16 + lg * 4 + r;
            pe += mask[n * 64 + row] * (C[mt][r] + bb);
        }
    pe += __shfl_xor(pe, 16, 64);
    pe += __shfl_xor(pe, 32, 64);
    if (lg == 0) out[(size_t)n * 64 + colc] = pe;
}

// ---------------- host launch ----------------
extern "C" void kernel_launch(void* const* d_in, const int* in_sizes, int n_in, void* d_out, int out_size,
                              void* d_ws, size_t ws_size, hipStream_t stream) {
    const float* W    = (const float*)d_in[0];
    const float* mask = (const float*)d_in[1];
    const int* src    = (const int*)d_in[2];
    const int* dst    = (const int*)d_in[3];
    const float* eps  = (const float*)d_in[4];
    const float* W1f  = (const float*)d_in[5];
    const float* b1f  = (const float*)d_in[6];
    const float* W1r  = (const float*)d_in[7];
    const float* b1r  = (const float*)d_in[8];
    const float* gam  = (const float*)d_in[9];
    const float* bet  = (const float*)d_in[10];
    const float* W2m  = (const float*)d_in[11];
    const float* b2m  = (const float*)d_in[12];
    const float* W2l  = (const float*)d_in[13];
    const float* b2l  = (const float*)d_in[14];
    float* out = (float*)d_out;

    // workspace layout
    ushort_t* Ha   = (ushort_t*)d_ws;          // 16,777,216
    ushort_t* Hb   = Ha + 16777216;            // 16,777,216
    ushort_t* w1t0 = Hb + 16777216;            // 4096
    ushort_t* w2lt = w1t0 + 4096;              // 8192
    ushort_t* w21t = w2lt + 8192;              // 49152
    float* bvec    = (float*)(w21t + 49152);   // 384
    int* ideg      = (int*)(bvec + 384);       // 2048
    int* icur      = ideg + 2048;              // 2048
    float* sums    = (float*)(icur + 2048);    // 1024 (4 layers x 256) -- zeroed with ideg/icur
    int* irp       = (int*)(sums + 1024);      // 2049
    int* icol      = irp + 2052;               // 16384

    // zero deg/cursor/sums in one kernel (contiguous 5120 words)
    zero_ints<<<20, 256, 0, stream>>>(ideg, 5120);
    count_deg<<<NEDGE / 256, 256, 0, stream>>>(dst, ideg);
    scan_deg<<<1, 256, 0, stream>>>(ideg, irp);
    fill_csr<<<NEDGE / 256, 256, 0, stream>>>(src, dst, irp, icur, icol);
    prep_small<<<50, 256, 0, stream>>>(W1f, W2l, b2m, W1r, w1t0, w2lt, bvec);
    prep_w21<<<192, 256, 0, stream>>>(W2m, W1r, w21t);

    // layer 0 (stats -> sums[0])
    gin_mm1_l0<<<N_SUM, 256, 0, stream>>>(W, w1t0, b1f, eps, irp, icol, Ha, sums);
    // layers 1..3 (consume sums[l-1], produce sums[l])
    gin_mm1_fused<<<N_SUM, 512, 0, stream>>>(Ha, w21t, b1r, bvec, sums, gam, bet, eps + 1,
                                             irp, icol, Hb, sums + 256);
    gin_mm1_fused<<<N_SUM, 512, 0, stream>>>(Hb, w21t + 16384, b1r + 128, bvec + 128, sums + 256,
                                             gam + 128, bet + 128, eps + 2, irp, icol, Ha, sums + 512);
    gin_mm1_fused<<<N_SUM, 512, 0, stream>>>(Ha, w21t + 32768, b1r + 256, bvec + 256, sums + 512,
                                             gam + 256, bet + 256, eps + 3, irp, icol, Hb, sums + 768);
    // final (consumes sums[3])
    gin_mm2_last<<<N_SUM, 256, 0, stream>>>(Hb, w2lt, b2l, sums + 768, gam + 384, bet + 384, mask, out);
}

// Round 8
// 369.521 us; speedup vs baseline: 1.0184x; 1.0140x over previous
//
#include <hip/hip_runtime.h>

#define N_SUM 2048
#define HIDD 128
#define NEDGE 16384
#define ROWS (N_SUM * 64)

typedef short short8 __attribute__((ext_vector_type(8)));
typedef float floatx4 __attribute__((ext_vector_type(4)));
typedef unsigned int uint4n __attribute__((ext_vector_type(4)));
typedef unsigned short ushort_t;

__device__ __forceinline__ ushort_t f2bf(float f) {
    unsigned u = __builtin_bit_cast(unsigned, f);
    u += 0x7fffu + ((u >> 16) & 1u);   // RNE
    return (ushort_t)(u >> 16);
}
__device__ __forceinline__ float bf2f(ushort_t h) {
    return __builtin_bit_cast(float, (unsigned)h << 16);
}
__device__ __forceinline__ void unpack8(uint4 v, float* f) {
    f[0] = bf2f(v.x & 0xffff); f[1] = bf2f(v.x >> 16);
    f[2] = bf2f(v.y & 0xffff); f[3] = bf2f(v.y >> 16);
    f[4] = bf2f(v.z & 0xffff); f[5] = bf2f(v.z >> 16);
    f[6] = bf2f(v.w & 0xffff); f[7] = bf2f(v.w >> 16);
}
__device__ __forceinline__ uint4 pack8(const float* f) {
    uint4 v;
    v.x = f2bf(f[0]) | ((unsigned)f2bf(f[1]) << 16);
    v.y = f2bf(f[2]) | ((unsigned)f2bf(f[3]) << 16);
    v.z = f2bf(f[4]) | ((unsigned)f2bf(f[5]) << 16);
    v.w = f2bf(f[6]) | ((unsigned)f2bf(f[7]) << 16);
    return v;
}
__device__ __forceinline__ void nt_store16(const void* src, void* dst) {
    __builtin_nontemporal_store(*(const uint4n*)src, (uint4n*)dst);
}

// ---------------- CSR build ----------------
__global__ __launch_bounds__(256) void zero_ints(int* p, int n) {
    int i = blockIdx.x * 256 + threadIdx.x;
    if (i < n) p[i] = 0;
}

__global__ __launch_bounds__(256) void count_deg(const int* __restrict__ dst, int* __restrict__ deg) {
    int e = blockIdx.x * 256 + threadIdx.x;
    if (e < NEDGE) atomicAdd(&deg[dst[e]], 1);
}

__global__ __launch_bounds__(256) void scan_deg(const int* __restrict__ deg, int* __restrict__ row_ptr) {
    __shared__ int csum[256];
    int t = threadIdx.x;
    int loc[8];
    int s = 0;
#pragma unroll
    for (int q = 0; q < 8; q++) { loc[q] = s; s += deg[t * 8 + q]; }
    csum[t] = s;
    __syncthreads();
    for (int off = 1; off < 256; off <<= 1) {
        int v = (t >= off) ? csum[t - off] : 0;
        __syncthreads();
        csum[t] += v;
        __syncthreads();
    }
    int base = (t == 0) ? 0 : csum[t - 1];
#pragma unroll
    for (int q = 0; q < 8; q++) row_ptr[t * 8 + q] = base + loc[q];
    if (t == 255) row_ptr[2048] = csum[255];
}

__global__ __launch_bounds__(256) void fill_csr(const int* __restrict__ src, const int* __restrict__ dst,
                                                const int* __restrict__ row_ptr, int* __restrict__ cursor,
                                                int* __restrict__ col) {
    int e = blockIdx.x * 256 + threadIdx.x;
    if (e < NEDGE) {
        int d = dst[e];
        int pos = atomicAdd(&cursor[d], 1);
        col[row_ptr[d] + pos] = src[e];
    }
}

// ---------------- weight prep ----------------
__global__ __launch_bounds__(256) void prep_small(const float* __restrict__ W1f, const float* __restrict__ W2l,
                                                  const float* __restrict__ b2m, const float* __restrict__ W1r,
                                                  ushort_t* __restrict__ w1t0, ushort_t* __restrict__ w2lt,
                                                  float* __restrict__ bvec) {
    int idx = blockIdx.x * 256 + threadIdx.x;
    if (idx < 4096) {
        int nn = idx >> 5, k = idx & 31;
        w1t0[idx] = f2bf(k < 16 ? W1f[k * 128 + nn] : 0.f);
    } else if (idx < 4096 + 8192) {
        int r = idx - 4096;
        int nn = r >> 7, k = r & 127;
        w2lt[r] = f2bf(W2l[k * 64 + nn]);
    } else if (idx < 4096 + 8192 + 384) {
        int r = idx - 12288;
        int lm = r >> 7, c = r & 127;
        float s = 0.f;
        for (int o = 0; o < 128; o++) s += b2m[lm * 128 + o] * W1r[(size_t)lm * 16384 + o * 128 + c];
        bvec[r] = s;
    }
}

// w21t[lm][c][i] = bf16( sum_o W2m[lm][i][o] * W1r[lm][o][c] )  -- B-fragment layout [n=c][k=i]
__global__ __launch_bounds__(256) void prep_w21(const float* __restrict__ W2m, const float* __restrict__ W1r,
                                                ushort_t* __restrict__ w21t) {
    int idx = blockIdx.x * 256 + threadIdx.x;  // 49152 total
    int lm = idx >> 14, r = idx & 16383, i = r >> 7, c = r & 127;
    const float* w2row = W2m + (size_t)lm * 16384 + i * 128;
    const float* w1col = W1r + (size_t)lm * 16384 + c;
    float s = 0.f;
#pragma unroll 8
    for (int o = 0; o < 128; o++) s += w2row[o] * w1col[o * 128];
    w21t[(size_t)lm * 16384 + c * 128 + i] = f2bf(s);
}

// A-layout for a 64x128 (or 64x32) bf16 tile: elem(m, k) at ((k>>3)*64 + m)*8 + (k&7)

// ---------------- layer 0: gather fp32 W + MFMA (K=16 padded to 32) ----------------
__global__ __launch_bounds__(256, 4) void gin_mm1_l0(const float* __restrict__ Xf, const ushort_t* __restrict__ W1t,
                                                     const float* __restrict__ b1, const float* __restrict__ eps,
                                                     const int* __restrict__ rp, const int* __restrict__ colv,
                                                     ushort_t* __restrict__ H, float* __restrict__ sums) {
    __shared__ ushort_t Zs[64 * 128];  // 16 KB
    int tid = threadIdx.x, n = blockIdx.x;
    float ev = 1.0f + eps[0];
    int e0 = rp[n], e1 = rp[n + 1], deg = e1 - e0;
    const float4* X = (const float4*)Xf;

    float4 sA, sB;
    sA = X[(size_t)n * 256 + tid];
    if (deg > 0) sB = X[(size_t)colv[e0] * 256 + tid];
    float4 a;
    a.x = sA.x * ev; a.y = sA.y * ev; a.z = sA.z * ev; a.w = sA.w * ev;
    int i = 1;
    for (; i + 1 < deg; i += 2) {
        sA = X[(size_t)colv[e0 + i] * 256 + tid];
        a.x += sB.x; a.y += sB.y; a.z += sB.z; a.w += sB.w;
        sB = X[(size_t)colv[e0 + i + 1] * 256 + tid];
        a.x += sA.x; a.y += sA.y; a.z += sA.z; a.w += sA.w;
    }
    if (deg > 0) {
        if (i < deg) {
            sA = X[(size_t)colv[e0 + i] * 256 + tid];
            a.x += sB.x; a.y += sB.y; a.z += sB.z; a.w += sB.w;
            a.x += sA.x; a.y += sA.y; a.z += sA.z; a.w += sA.w;
        } else {
            a.x += sB.x; a.y += sB.y; a.z += sB.z; a.w += sB.w;
        }
    }

    {
        int m = tid >> 2, k0 = (tid & 3) * 4;
        int addr = ((k0 >> 3) * 64 + m) * 8 + (k0 & 7);
        uint2 pv;
        pv.x = f2bf(a.x) | ((unsigned)f2bf(a.y) << 16);
        pv.y = f2bf(a.z) | ((unsigned)f2bf(a.w) << 16);
        *(uint2*)&Zs[addr] = pv;
        *(uint2*)&Zs[1024 + tid * 4] = make_uint2(0u, 0u);
    }
    __syncthreads();

    int w = tid >> 6, lane = tid & 63, lg = lane >> 4, ln = lane & 15;
    floatx4 C[4][2];
#pragma unroll
    for (int mt = 0; mt < 4; mt++) { C[mt][0] = {0.f, 0.f, 0.f, 0.f}; C[mt][1] = {0.f, 0.f, 0.f, 0.f}; }

    {
        short8 B0 = *(const short8*)&W1t[(w * 32 + ln) * 32 + lg * 8];
        short8 B1 = *(const short8*)&W1t[(w * 32 + 16 + ln) * 32 + lg * 8];
#pragma unroll
        for (int mt = 0; mt < 4; mt++) {
            short8 A = *(const short8*)&Zs[(lg * 64 + mt * 16 + ln) * 8];
            C[mt][0] = __builtin_amdgcn_mfma_f32_16x16x32_bf16(A, B0, C[mt][0], 0, 0, 0);
            C[mt][1] = __builtin_amdgcn_mfma_f32_16x16x32_bf16(A, B1, C[mt][1], 0, 0, 0);
        }
    }

    float bsum[2], bsq[2];
    float bv[2] = {b1[w * 32 + ln], b1[w * 32 + 16 + ln]};
#pragma unroll
    for (int nt = 0; nt < 2; nt++) {
        float s = 0.f, s2 = 0.f;
#pragma unroll
        for (int mt = 0; mt < 4; mt++)
#pragma unroll
            for (int r = 0; r < 4; r++) {
                float v = C[mt][nt][r] + bv[nt];
                C[mt][nt][r] = v;
                s += v; s2 += v * v;
            }
        bsum[nt] = s; bsq[nt] = s2;
    }
#pragma unroll
    for (int nt = 0; nt < 2; nt++) {
        bsum[nt] += __shfl_xor(bsum[nt], 16, 64);
        bsum[nt] += __shfl_xor(bsum[nt], 32, 64);
        bsq[nt] += __shfl_xor(bsq[nt], 16, 64);
        bsq[nt] += __shfl_xor(bsq[nt], 32, 64);
    }
    if (lg == 0) {
        int c0 = w * 32 + ln;
        atomicAdd(&sums[c0], bsum[0]);
        atomicAdd(&sums[c0 + 16], bsum[1]);
        atomicAdd(&sums[128 + c0], bsq[0]);
        atomicAdd(&sums[128 + c0 + 16], bsq[1]);
    }
    __syncthreads();
#pragma unroll
    for (int nt = 0; nt < 2; nt++) {
        int colc = w * 32 + nt * 16 + ln;
        int base = (colc >> 3) * 512 + (colc & 7);
#pragma unroll
        for (int mt = 0; mt < 4; mt++)
#pragma unroll
            for (int r = 0; r < 4; r++) {
                int row = mt * 16 + lg * 4 + r;
                Zs[base + row * 8] = f2bf(C[mt][nt][r]);
            }
    }
    __syncthreads();
#pragma unroll
    for (int q = 0; q < 4; q++)
        nt_store16(&((const uint4*)Zs)[q * 256 + tid], &((uint4*)&H[(size_t)n * 8192])[q * 256 + tid]);
}

// ---------------- fused layers 1..3 (512 threads, r5 scalar math, 2-deep pipeline) ----------------
// Computes scale/shift from previous layer's atomic sums per block, gathers
// relu(bn(Hin)), matmul by W21 = W2[l-1]@W1[l], bias = b1 + (1+eps+deg)*bvec;
// accumulates this layer's BN sums via atomicAdd.
__global__ __launch_bounds__(512, 4) void gin_mm1_fused(const ushort_t* __restrict__ Hin,
                                                        const ushort_t* __restrict__ W21t,
                                                        const float* __restrict__ b1, const float* __restrict__ bvec,
                                                        const float* __restrict__ sums_prev,
                                                        const float* __restrict__ gam_prev,
                                                        const float* __restrict__ bet_prev,
                                                        const float* __restrict__ epsp,
                                                        const int* __restrict__ rp, const int* __restrict__ colv,
                                                        ushort_t* __restrict__ Hout, float* __restrict__ sums_cur) {
    __shared__ ushort_t Zs[64 * 128];   // 16 KB
    __shared__ float scs_lds[256];      // 1 KB
    int tid = threadIdx.x, n = blockIdx.x;
    if (tid < 128) {
        float mean = sums_prev[tid] * (1.f / (float)ROWS);
        float var = sums_prev[128 + tid] * (1.f / (float)ROWS) - mean * mean;
        float sc = gam_prev[tid] * rsqrtf(var + 1e-5f);
        scs_lds[tid] = sc;
        scs_lds[128 + tid] = bet_prev[tid] - mean * sc;
    }
    __syncthreads();

    // r5-style packed BN params: scale in low 16 bits, shift in high 16 bits (bf16 each)
    unsigned scp[2][8];
#pragma unroll
    for (int q = 0; q < 2; q++) {
        int cb = ((q * 512 + tid) >> 6) * 8;
#pragma unroll
        for (int j = 0; j < 8; j++)
            scp[q][j] = ((unsigned)f2bf(scs_lds[cb + j])) | ((unsigned)f2bf(scs_lds[128 + cb + j]) << 16);
    }

    float ev = 1.0f + epsp[0];
    int e0 = rp[n], e1 = rp[n + 1], deg = e1 - e0;
    const uint4* X = (const uint4*)Hin;
    float acc[2][8];
    uint4 bufA[2], bufB[2];

    auto loadslab = [&](uint4* buf, int node) {
        const uint4* p = X + (size_t)node * 1024;
        buf[0] = p[tid];
        buf[1] = p[512 + tid];
    };
    auto addp = [&](const uint4* buf) {
#pragma unroll
        for (int q = 0; q < 2; q++) {
            float f[8]; unpack8(buf[q], f);
#pragma unroll
            for (int j = 0; j < 8; j++) {
                float sc = __builtin_bit_cast(float, scp[q][j] << 16);
                float sh = __builtin_bit_cast(float, scp[q][j] & 0xffff0000u);
                acc[q][j] += fmaxf(fmaf(f[j], sc, sh), 0.f);
            }
        }
    };

    loadslab(bufA, n);
    if (deg > 0) loadslab(bufB, colv[e0]);

    // self: acc = ev * relu(x*sc + sh)
#pragma unroll
    for (int q = 0; q < 2; q++) {
        float f[8]; unpack8(bufA[q], f);
#pragma unroll
        for (int j = 0; j < 8; j++) {
            float sc = __builtin_bit_cast(float, scp[q][j] << 16);
            float sh = __builtin_bit_cast(float, scp[q][j] & 0xffff0000u);
            acc[q][j] = ev * fmaxf(fmaf(f[j], sc, sh), 0.f);
        }
    }

    int i = 1;
    for (; i + 1 < deg; i += 2) {
        loadslab(bufA, colv[e0 + i]);
        addp(bufB);
        loadslab(bufB, colv[e0 + i + 1]);
        addp(bufA);
    }
    if (deg > 0) {
        if (i < deg) {
            loadslab(bufA, colv[e0 + i]);
            addp(bufB);
            addp(bufA);
        } else {
            addp(bufB);
        }
    }

#pragma unroll
    for (int q = 0; q < 2; q++) ((uint4*)Zs)[q * 512 + tid] = pack8(acc[q]);
    __syncthreads();

    // MFMA: 8 waves, each owns 16 output cols, all 64 rows (4 M-tiles)
    int w = tid >> 6, lane = tid & 63, lg = lane >> 4, ln = lane & 15;
    floatx4 C[4];
#pragma unroll
    for (int mt = 0; mt < 4; mt++) C[mt] = {0.f, 0.f, 0.f, 0.f};

    for (int kb = 0; kb < 4; kb++) {
        short8 B = *(const short8*)&W21t[(w * 16 + ln) * 128 + kb * 32 + lg * 8];
#pragma unroll
        for (int mt = 0; mt < 4; mt++) {
            short8 A = *(const short8*)&Zs[((kb * 4 + lg) * 64 + mt * 16 + ln) * 8];
            C[mt] = __builtin_amdgcn_mfma_f32_16x16x32_bf16(A, B, C[mt], 0, 0, 0);
        }
    }

    float fac = ev + (float)deg;
    int c0 = w * 16 + ln;
    float bv = b1[c0] + fac * bvec[c0];
    float s = 0.f, s2 = 0.f;
#pragma unroll
    for (int mt = 0; mt < 4; mt++)
#pragma unroll
        for (int r = 0; r < 4; r++) {
            float v = C[mt][r] + bv;
            C[mt][r] = v;
            s += v; s2 += v * v;
        }
    s += __shfl_xor(s, 16, 64);
    s += __shfl_xor(s, 32, 64);
    s2 += __shfl_xor(s2, 16, 64);
    s2 += __shfl_xor(s2, 32, 64);
    if (lg == 0) {
        atomicAdd(&sums_cur[c0], s);
        atomicAdd(&sums_cur[128 + c0], s2);
    }

    __syncthreads();
    {
        int base = (c0 >> 3) * 512 + (c0 & 7);
#pragma unroll
        for (int mt = 0; mt < 4; mt++)
#pragma unroll
            for (int r = 0; r < 4; r++) {
                int row = mt * 16 + lg * 4 + r;
                Zs[base + row * 8] = f2bf(C[mt][r]);
            }
    }
    __syncthreads();
#pragma unroll
    for (int q = 0; q < 2; q++)
        nt_store16(&((const uint4*)Zs)[q * 512 + tid], &((uint4*)&Hout[(size_t)n * 8192])[q * 512 + tid]);
}

// ---------------- final: PE = sum_rows mask * (relu(bn(H3)) @ W2l + b2l) ----------------
__global__ __launch_bounds__(256, 4) void gin_mm2_last(const ushort_t* __restrict__ H, const ushort_t* __restrict__ W2t,
                                                       const float* __restrict__ b2,
                                                       const float* __restrict__ sums_prev,
                                                       const float* __restrict__ gam_prev,
                                                       const float* __restrict__ bet_prev,
                                                       const float* __restrict__ mask, float* __restrict__ out) {
    __shared__ ushort_t Hs[64 * 128];
    __shared__ float scs_lds[256];
    int tid = threadIdx.x, n = blockIdx.x;
    if (tid < 128) {
        float mean = sums_prev[tid] * (1.f / (float)ROWS);
        float var = sums_prev[128 + tid] * (1.f / (float)ROWS) - mean * mean;
        float sc = gam_prev[tid] * rsqrtf(var + 1e-5f);
        scs_lds[tid] = sc;
        scs_lds[128 + tid] = bet_prev[tid] - mean * sc;
    }
    __syncthreads();

#pragma unroll
    for (int q = 0; q < 4; q++) {
        int c = q * 256 + tid;
        uint4 v = ((const uint4*)&H[(size_t)n * 8192])[c];
        float f[8]; unpack8(v, f);
        int cb = (c >> 6) * 8;
#pragma unroll
        for (int j = 0; j < 8; j++) f[j] = fmaxf(fmaf(f[j], scs_lds[cb + j], scs_lds[128 + cb + j]), 0.f);
        ((uint4*)Hs)[c] = pack8(f);
    }
    __syncthreads();

    int w = tid >> 6, lane = tid & 63, lg = lane >> 4, ln = lane & 15;
    floatx4 C[4];
#pragma unroll
    for (int mt = 0; mt < 4; mt++) C[mt] = {0.f, 0.f, 0.f, 0.f};

    for (int kb = 0; kb < 4; kb++) {
        short8 B = *(const short8*)&W2t[(w * 16 + ln) * 128 + kb * 32 + lg * 8];
#pragma unroll
        for (int mt = 0; mt < 4; mt++) {
            short8 A = *(const short8*)&Hs[((kb * 4 + lg) * 64 + mt * 16 + ln) * 8];
            C[mt] = __builtin_amdgcn_mfma_f32_16x16x32_bf16(A, B, C[mt], 0, 0, 0);
        }
    }

    int colc = w * 16 + ln;
    float bb = b2[colc];
    float pe = 0.f;
#pragma unroll
    for (int mt = 0; mt < 4; mt++)
#pragma unroll
        for (int r = 0; r < 4; r++) {
            int row = mt * 16 + lg * 4 + r;
            pe += mask[n * 64 + row] * (C[mt][r] + bb);
        }
    pe += __shfl_xor(pe, 16, 64);
    pe += __shfl_xor(pe, 32, 64);
    if (lg == 0) out[(size_t)n * 64 + colc] = pe;
}

// ---------------- host launch ----------------
extern "C" void kernel_launch(void* const* d_in, const int* in_sizes, int n_in, void* d_out, int out_size,
                              void* d_ws, size_t ws_size, hipStream_t stream) {
    const float* W    = (const float*)d_in[0];
    const float* mask = (const float*)d_in[1];
    const int* src    = (const int*)d_in[2];
    const int* dst    = (const int*)d_in[3];
    const float* eps  = (const float*)d_in[4];
    const float* W1f  = (const float*)d_in[5];
    const float* b1f  = (const float*)d_in[6];
    const float* W1r  = (const float*)d_in[7];
    const float* b1r  = (const float*)d_in[8];
    const float* gam  = (const float*)d_in[9];
    const float* bet  = (const float*)d_in[10];
    const float* W2m  = (const float*)d_in[11];
    const float* b2m  = (const float*)d_in[12];
    const float* W2l  = (const float*)d_in[13];
    const float* b2l  = (const float*)d_in[14];
    float* out = (float*)d_out;

    // workspace layout
    ushort_t* Ha   = (ushort_t*)d_ws;          // 16,777,216
    ushort_t* Hb   = Ha + 16777216;            // 16,777,216
    ushort_t* w1t0 = Hb + 16777216;            // 4096
    ushort_t* w2lt = w1t0 + 4096;              // 8192
    ushort_t* w21t = w2lt + 8192;              // 49152
    float* bvec    = (float*)(w21t + 49152);   // 384
    int* ideg      = (int*)(bvec + 384);       // 2048
    int* icur      = ideg + 2048;              // 2048
    float* sums    = (float*)(icur + 2048);    // 1024 (4 layers x 256) -- zeroed with ideg/icur
    int* irp       = (int*)(sums + 1024);      // 2049
    int* icol      = irp + 2052;               // 16384

    // zero deg/cursor/sums in one kernel (contiguous 5120 words)
    zero_ints<<<20, 256, 0, stream>>>(ideg, 5120);
    count_deg<<<NEDGE / 256, 256, 0, stream>>>(dst, ideg);
    scan_deg<<<1, 256, 0, stream>>>(ideg, irp);
    fill_csr<<<NEDGE / 256, 256, 0, stream>>>(src, dst, irp, icur, icol);
    prep_small<<<50, 256, 0, stream>>>(W1f, W2l, b2m, W1r, w1t0, w2lt, bvec);
    prep_w21<<<192, 256, 0, stream>>>(W2m, W1r, w21t);

    // layer 0 (stats -> sums[0])
    gin_mm1_l0<<<N_SUM, 256, 0, stream>>>(W, w1t0, b1f, eps, irp, icol, Ha, sums);
    // layers 1..3 (consume sums[l-1], produce sums[l])
    gin_mm1_fused<<<N_SUM, 512, 0, stream>>>(Ha, w21t, b1r, bvec, sums, gam, bet, eps + 1,
                                             irp, icol, Hb, sums + 256);
    gin_mm1_fused<<<N_SUM, 512, 0, stream>>>(Hb, w21t + 16384, b1r + 128, bvec + 128, sums + 256,
                                             gam + 128, bet + 128, eps + 2, irp, icol, Ha, sums + 512);
    gin_mm1_fused<<<N_SUM, 512, 0, stream>>>(Ha, w21t + 32768, b1r + 256, bvec + 256, sums + 512,
                                             gam + 256, bet + 256, eps + 3, irp, icol, Hb, sums + 768);
    // final (consumes sums[3])
    gin_mm2_last<<<N_SUM, 256, 0, stream>>>(Hb, w2lt, b2l, sums + 768, gam + 384, bet + 384, mask, out);
}

// Round 9
// 273.359 us; speedup vs baseline: 1.3767x; 1.3518x over previous
//
#include <hip/hip_runtime.h>

#define N_SUM 2048
#define HIDD 128
#define NEDGE 16384
#define ROWS (N_SUM * 64)
#define NSLOT 16

typedef short short8 __attribute__((ext_vector_type(8)));
typedef float floatx4 __attribute__((ext_vector_type(4)));
typedef unsigned int uint4n __attribute__((ext_vector_type(4)));
typedef unsigned short ushort_t;

__device__ __forceinline__ ushort_t f2bf(float f) {
    unsigned u = __builtin_bit_cast(unsigned, f);
    u += 0x7fffu + ((u >> 16) & 1u);   // RNE
    return (ushort_t)(u >> 16);
}
__device__ __forceinline__ float bf2f(ushort_t h) {
    return __builtin_bit_cast(float, (unsigned)h << 16);
}
__device__ __forceinline__ void unpack8(uint4 v, float* f) {
    f[0] = bf2f(v.x & 0xffff); f[1] = bf2f(v.x >> 16);
    f[2] = bf2f(v.y & 0xffff); f[3] = bf2f(v.y >> 16);
    f[4] = bf2f(v.z & 0xffff); f[5] = bf2f(v.z >> 16);
    f[6] = bf2f(v.w & 0xffff); f[7] = bf2f(v.w >> 16);
}
__device__ __forceinline__ uint4 pack8(const float* f) {
    uint4 v;
    v.x = f2bf(f[0]) | ((unsigned)f2bf(f[1]) << 16);
    v.y = f2bf(f[2]) | ((unsigned)f2bf(f[3]) << 16);
    v.z = f2bf(f[4]) | ((unsigned)f2bf(f[5]) << 16);
    v.w = f2bf(f[6]) | ((unsigned)f2bf(f[7]) << 16);
    return v;
}
__device__ __forceinline__ void nt_store16(const void* src, void* dst) {
    __builtin_nontemporal_store(*(const uint4n*)src, (uint4n*)dst);
}

// ---------------- CSR build ----------------
__global__ __launch_bounds__(256) void zero_ints(int* p, int n) {
    int i = blockIdx.x * 256 + threadIdx.x;
    if (i < n) p[i] = 0;
}

__global__ __launch_bounds__(256) void count_deg(const int* __restrict__ dst, int* __restrict__ deg) {
    int e = blockIdx.x * 256 + threadIdx.x;
    if (e < NEDGE) atomicAdd(&deg[dst[e]], 1);
}

__global__ __launch_bounds__(256) void scan_deg(const int* __restrict__ deg, int* __restrict__ row_ptr) {
    __shared__ int csum[256];
    int t = threadIdx.x;
    int loc[8];
    int s = 0;
#pragma unroll
    for (int q = 0; q < 8; q++) { loc[q] = s; s += deg[t * 8 + q]; }
    csum[t] = s;
    __syncthreads();
    for (int off = 1; off < 256; off <<= 1) {
        int v = (t >= off) ? csum[t - off] : 0;
        __syncthreads();
        csum[t] += v;
        __syncthreads();
    }
    int base = (t == 0) ? 0 : csum[t - 1];
#pragma unroll
    for (int q = 0; q < 8; q++) row_ptr[t * 8 + q] = base + loc[q];
    if (t == 255) row_ptr[2048] = csum[255];
}

__global__ __launch_bounds__(256) void fill_csr(const int* __restrict__ src, const int* __restrict__ dst,
                                                const int* __restrict__ row_ptr, int* __restrict__ cursor,
                                                int* __restrict__ col) {
    int e = blockIdx.x * 256 + threadIdx.x;
    if (e < NEDGE) {
        int d = dst[e];
        int pos = atomicAdd(&cursor[d], 1);
        col[row_ptr[d] + pos] = src[e];
    }
}

// ---------------- weight prep ----------------
__global__ __launch_bounds__(256) void prep_small(const float* __restrict__ W1f, const float* __restrict__ W2l,
                                                  const float* __restrict__ b2m, const float* __restrict__ W1r,
                                                  ushort_t* __restrict__ w1t0, ushort_t* __restrict__ w2lt,
                                                  float* __restrict__ bvec) {
    int idx = blockIdx.x * 256 + threadIdx.x;
    if (idx < 4096) {
        int nn = idx >> 5, k = idx & 31;
        w1t0[idx] = f2bf(k < 16 ? W1f[k * 128 + nn] : 0.f);
    } else if (idx < 4096 + 8192) {
        int r = idx - 4096;
        int nn = r >> 7, k = r & 127;
        w2lt[r] = f2bf(W2l[k * 64 + nn]);
    } else if (idx < 4096 + 8192 + 384) {
        int r = idx - 12288;
        int lm = r >> 7, c = r & 127;
        float s = 0.f;
        for (int o = 0; o < 128; o++) s += b2m[lm * 128 + o] * W1r[(size_t)lm * 16384 + o * 128 + c];
        bvec[r] = s;
    }
}

// w21t[lm][c][i] = bf16( sum_o W2m[lm][i][o] * W1r[lm][o][c] )  -- B-fragment layout [n=c][k=i]
__global__ __launch_bounds__(256) void prep_w21(const float* __restrict__ W2m, const float* __restrict__ W1r,
                                                ushort_t* __restrict__ w21t) {
    int idx = blockIdx.x * 256 + threadIdx.x;  // 49152 total
    int lm = idx >> 14, r = idx & 16383, i = r >> 7, c = r & 127;
    const float* w2row = W2m + (size_t)lm * 16384 + i * 128;
    const float* w1col = W1r + (size_t)lm * 16384 + c;
    float s = 0.f;
#pragma unroll 8
    for (int o = 0; o < 128; o++) s += w2row[o] * w1col[o * 128];
    w21t[(size_t)lm * 16384 + c * 128 + i] = f2bf(s);
}

// A-layout for a 64x128 (or 64x32) bf16 tile: elem(m, k) at ((k>>3)*64 + m)*8 + (k&7)

// ---------------- layer 0: gather fp32 W + MFMA (K=16 padded to 32) ----------------
// BN sums into replicated slot (blockIdx & 15) to avoid atomic contention.
__global__ __launch_bounds__(256, 4) void gin_mm1_l0(const float* __restrict__ Xf, const ushort_t* __restrict__ W1t,
                                                     const float* __restrict__ b1, const float* __restrict__ eps,
                                                     const int* __restrict__ rp, const int* __restrict__ colv,
                                                     ushort_t* __restrict__ H, float* __restrict__ sums) {
    __shared__ ushort_t Zs[64 * 128];  // 16 KB
    int tid = threadIdx.x, n = blockIdx.x;
    float ev = 1.0f + eps[0];
    int e0 = rp[n], e1 = rp[n + 1], deg = e1 - e0;
    const float4* X = (const float4*)Xf;

    float4 sA, sB;
    sA = X[(size_t)n * 256 + tid];
    if (deg > 0) sB = X[(size_t)colv[e0] * 256 + tid];
    float4 a;
    a.x = sA.x * ev; a.y = sA.y * ev; a.z = sA.z * ev; a.w = sA.w * ev;
    int i = 1;
    for (; i + 1 < deg; i += 2) {
        sA = X[(size_t)colv[e0 + i] * 256 + tid];
        a.x += sB.x; a.y += sB.y; a.z += sB.z; a.w += sB.w;
        sB = X[(size_t)colv[e0 + i + 1] * 256 + tid];
        a.x += sA.x; a.y += sA.y; a.z += sA.z; a.w += sA.w;
    }
    if (deg > 0) {
        if (i < deg) {
            sA = X[(size_t)colv[e0 + i] * 256 + tid];
            a.x += sB.x; a.y += sB.y; a.z += sB.z; a.w += sB.w;
            a.x += sA.x; a.y += sA.y; a.z += sA.z; a.w += sA.w;
        } else {
            a.x += sB.x; a.y += sB.y; a.z += sB.z; a.w += sB.w;
        }
    }

    {
        int m = tid >> 2, k0 = (tid & 3) * 4;
        int addr = ((k0 >> 3) * 64 + m) * 8 + (k0 & 7);
        uint2 pv;
        pv.x = f2bf(a.x) | ((unsigned)f2bf(a.y) << 16);
        pv.y = f2bf(a.z) | ((unsigned)f2bf(a.w) << 16);
        *(uint2*)&Zs[addr] = pv;
        *(uint2*)&Zs[1024 + tid * 4] = make_uint2(0u, 0u);
    }
    __syncthreads();

    int w = tid >> 6, lane = tid & 63, lg = lane >> 4, ln = lane & 15;
    floatx4 C[4][2];
#pragma unroll
    for (int mt = 0; mt < 4; mt++) { C[mt][0] = {0.f, 0.f, 0.f, 0.f}; C[mt][1] = {0.f, 0.f, 0.f, 0.f}; }

    {
        short8 B0 = *(const short8*)&W1t[(w * 32 + ln) * 32 + lg * 8];
        short8 B1 = *(const short8*)&W1t[(w * 32 + 16 + ln) * 32 + lg * 8];
#pragma unroll
        for (int mt = 0; mt < 4; mt++) {
            short8 A = *(const short8*)&Zs[(lg * 64 + mt * 16 + ln) * 8];
            C[mt][0] = __builtin_amdgcn_mfma_f32_16x16x32_bf16(A, B0, C[mt][0], 0, 0, 0);
            C[mt][1] = __builtin_amdgcn_mfma_f32_16x16x32_bf16(A, B1, C[mt][1], 0, 0, 0);
        }
    }

    float bsum[2], bsq[2];
    float bv[2] = {b1[w * 32 + ln], b1[w * 32 + 16 + ln]};
#pragma unroll
    for (int nt = 0; nt < 2; nt++) {
        float s = 0.f, s2 = 0.f;
#pragma unroll
        for (int mt = 0; mt < 4; mt++)
#pragma unroll
            for (int r = 0; r < 4; r++) {
                float v = C[mt][nt][r] + bv[nt];
                C[mt][nt][r] = v;
                s += v; s2 += v * v;
            }
        bsum[nt] = s; bsq[nt] = s2;
    }
#pragma unroll
    for (int nt = 0; nt < 2; nt++) {
        bsum[nt] += __shfl_xor(bsum[nt], 16, 64);
        bsum[nt] += __shfl_xor(bsum[nt], 32, 64);
        bsq[nt] += __shfl_xor(bsq[nt], 16, 64);
        bsq[nt] += __shfl_xor(bsq[nt], 32, 64);
    }
    if (lg == 0) {
        float* sl = sums + (n & (NSLOT - 1)) * 256;
        int c0 = w * 32 + ln;
        atomicAdd(&sl[c0], bsum[0]);
        atomicAdd(&sl[c0 + 16], bsum[1]);
        atomicAdd(&sl[128 + c0], bsq[0]);
        atomicAdd(&sl[128 + c0 + 16], bsq[1]);
    }
    __syncthreads();
#pragma unroll
    for (int nt = 0; nt < 2; nt++) {
        int colc = w * 32 + nt * 16 + ln;
        int base = (colc >> 3) * 512 + (colc & 7);
#pragma unroll
        for (int mt = 0; mt < 4; mt++)
#pragma unroll
            for (int r = 0; r < 4; r++) {
                int row = mt * 16 + lg * 4 + r;
                Zs[base + row * 8] = f2bf(C[mt][nt][r]);
            }
    }
    __syncthreads();
#pragma unroll
    for (int q = 0; q < 4; q++)
        nt_store16(&((const uint4*)Zs)[q * 256 + tid], &((uint4*)&H[(size_t)n * 8192])[q * 256 + tid]);
}

// ---------------- fused layers 1..3 (512 threads, r5 scalar math, 2-deep pipeline) ----------------
// scale/shift recomputed from slot-replicated sums; this layer's sums into slots too.
__global__ __launch_bounds__(512, 4) void gin_mm1_fused(const ushort_t* __restrict__ Hin,
                                                        const ushort_t* __restrict__ W21t,
                                                        const float* __restrict__ b1, const float* __restrict__ bvec,
                                                        const float* __restrict__ sums_prev,
                                                        const float* __restrict__ gam_prev,
                                                        const float* __restrict__ bet_prev,
                                                        const float* __restrict__ epsp,
                                                        const int* __restrict__ rp, const int* __restrict__ colv,
                                                        ushort_t* __restrict__ Hout, float* __restrict__ sums_cur) {
    __shared__ ushort_t Zs[64 * 128];   // 16 KB
    __shared__ float scs_lds[256];      // 1 KB
    int tid = threadIdx.x, n = blockIdx.x;
    if (tid < 128) {
        float s = 0.f, s2 = 0.f;
#pragma unroll
        for (int k = 0; k < NSLOT; k++) {
            s += sums_prev[k * 256 + tid];
            s2 += sums_prev[k * 256 + 128 + tid];
        }
        float mean = s * (1.f / (float)ROWS);
        float var = s2 * (1.f / (float)ROWS) - mean * mean;
        float sc = gam_prev[tid] * rsqrtf(var + 1e-5f);
        scs_lds[tid] = sc;
        scs_lds[128 + tid] = bet_prev[tid] - mean * sc;
    }
    __syncthreads();

    // packed BN params: scale bf16 in low 16 bits, shift bf16 in high 16 bits
    unsigned scp[2][8];
#pragma unroll
    for (int q = 0; q < 2; q++) {
        int cb = ((q * 512 + tid) >> 6) * 8;
#pragma unroll
        for (int j = 0; j < 8; j++)
            scp[q][j] = ((unsigned)f2bf(scs_lds[cb + j])) | ((unsigned)f2bf(scs_lds[128 + cb + j]) << 16);
    }

    float ev = 1.0f + epsp[0];
    int e0 = rp[n], e1 = rp[n + 1], deg = e1 - e0;
    const uint4* X = (const uint4*)Hin;
    float acc[2][8];
    uint4 bufA[2], bufB[2];

    auto loadslab = [&](uint4* buf, int node) {
        const uint4* p = X + (size_t)node * 1024;
        buf[0] = p[tid];
        buf[1] = p[512 + tid];
    };
    auto addp = [&](const uint4* buf) {
#pragma unroll
        for (int q = 0; q < 2; q++) {
            float f[8]; unpack8(buf[q], f);
#pragma unroll
            for (int j = 0; j < 8; j++) {
                float sc = __builtin_bit_cast(float, scp[q][j] << 16);
                float sh = __builtin_bit_cast(float, scp[q][j] & 0xffff0000u);
                acc[q][j] += fmaxf(fmaf(f[j], sc, sh), 0.f);
            }
        }
    };

    loadslab(bufA, n);
    if (deg > 0) loadslab(bufB, colv[e0]);

    // self: acc = ev * relu(x*sc + sh)
#pragma unroll
    for (int q = 0; q < 2; q++) {
        float f[8]; unpack8(bufA[q], f);
#pragma unroll
        for (int j = 0; j < 8; j++) {
            float sc = __builtin_bit_cast(float, scp[q][j] << 16);
            float sh = __builtin_bit_cast(float, scp[q][j] & 0xffff0000u);
            acc[q][j] = ev * fmaxf(fmaf(f[j], sc, sh), 0.f);
        }
    }

    int i = 1;
    for (; i + 1 < deg; i += 2) {
        loadslab(bufA, colv[e0 + i]);
        addp(bufB);
        loadslab(bufB, colv[e0 + i + 1]);
        addp(bufA);
    }
    if (deg > 0) {
        if (i < deg) {
            loadslab(bufA, colv[e0 + i]);
            addp(bufB);
            addp(bufA);
        } else {
            addp(bufB);
        }
    }

#pragma unroll
    for (int q = 0; q < 2; q++) ((uint4*)Zs)[q * 512 + tid] = pack8(acc[q]);
    __syncthreads();

    // MFMA: 8 waves, each owns 16 output cols, all 64 rows (4 M-tiles)
    int w = tid >> 6, lane = tid & 63, lg = lane >> 4, ln = lane & 15;
    floatx4 C[4];
#pragma unroll
    for (int mt = 0; mt < 4; mt++) C[mt] = {0.f, 0.f, 0.f, 0.f};

    for (int kb = 0; kb < 4; kb++) {
        short8 B = *(const short8*)&W21t[(w * 16 + ln) * 128 + kb * 32 + lg * 8];
#pragma unroll
        for (int mt = 0; mt < 4; mt++) {
            short8 A = *(const short8*)&Zs[((kb * 4 + lg) * 64 + mt * 16 + ln) * 8];
            C[mt] = __builtin_amdgcn_mfma_f32_16x16x32_bf16(A, B, C[mt], 0, 0, 0);
        }
    }

    float fac = ev + (float)deg;
    int c0 = w * 16 + ln;
    float bv = b1[c0] + fac * bvec[c0];
    float s = 0.f, s2 = 0.f;
#pragma unroll
    for (int mt = 0; mt < 4; mt++)
#pragma unroll
        for (int r = 0; r < 4; r++) {
            float v = C[mt][r] + bv;
            C[mt][r] = v;
            s += v; s2 += v * v;
        }
    s += __shfl_xor(s, 16, 64);
    s += __shfl_xor(s, 32, 64);
    s2 += __shfl_xor(s2, 16, 64);
    s2 += __shfl_xor(s2, 32, 64);
    if (lg == 0) {
        float* sl = sums_cur + (n & (NSLOT - 1)) * 256;
        atomicAdd(&sl[c0], s);
        atomicAdd(&sl[128 + c0], s2);
    }

    __syncthreads();
    {
        int base = (c0 >> 3) * 512 + (c0 & 7);
#pragma unroll
        for (int mt = 0; mt < 4; mt++)
#pragma unroll
            for (int r = 0; r < 4; r++) {
                int row = mt * 16 + lg * 4 + r;
                Zs[base + row * 8] = f2bf(C[mt][r]);
            }
    }
    __syncthreads();
#pragma unroll
    for (int q = 0; q < 2; q++)
        nt_store16(&((const uint4*)Zs)[q * 512 + tid], &((uint4*)&Hout[(size_t)n * 8192])[q * 512 + tid]);
}

// ---------------- final: PE = sum_rows mask * (relu(bn(H3)) @ W2l + b2l) ----------------
__global__ __launch_bounds__(256, 4) void gin_mm2_last(const ushort_t* __restrict__ H, const ushort_t* __restrict__ W2t,
                                                       const float* __restrict__ b2,
                                                       const float* __restrict__ sums_prev,
                                                       const float* __restrict__ gam_prev,
                                                       const float* __restrict__ bet_prev,
                                                       const float* __restrict__ mask, float* __restrict__ out) {
    __shared__ ushort_t Hs[64 * 128];
    __shared__ float scs_lds[256];
    int tid = threadIdx.x, n = blockIdx.x;
    if (tid < 128) {
        float s = 0.f, s2 = 0.f;
#pragma unroll
        for (int k = 0; k < NSLOT; k++) {
            s += sums_prev[k * 256 + tid];
            s2 += sums_prev[k * 256 + 128 + tid];
        }
        float mean = s * (1.f / (float)ROWS);
        float var = s2 * (1.f / (float)ROWS) - mean * mean;
        float sc = gam_prev[tid] * rsqrtf(var + 1e-5f);
        scs_lds[tid] = sc;
        scs_lds[128 + tid] = bet_prev[tid] - mean * sc;
    }
    __syncthreads();

#pragma unroll
    for (int q = 0; q < 4; q++) {
        int c = q * 256 + tid;
        uint4 v = ((const uint4*)&H[(size_t)n * 8192])[c];
        float f[8]; unpack8(v, f);
        int cb = (c >> 6) * 8;
#pragma unroll
        for (int j = 0; j < 8; j++) f[j] = fmaxf(fmaf(f[j], scs_lds[cb + j], scs_lds[128 + cb + j]), 0.f);
        ((uint4*)Hs)[c] = pack8(f);
    }
    __syncthreads();

    int w = tid >> 6, lane = tid & 63, lg = lane >> 4, ln = lane & 15;
    floatx4 C[4];
#pragma unroll
    for (int mt = 0; mt < 4; mt++) C[mt] = {0.f, 0.f, 0.f, 0.f};

    for (int kb = 0; kb < 4; kb++) {
        short8 B = *(const short8*)&W2t[(w * 16 + ln) * 128 + kb * 32 + lg * 8];
#pragma unroll
        for (int mt = 0; mt < 4; mt++) {
            short8 A = *(const short8*)&Hs[((kb * 4 + lg) * 64 + mt * 16 + ln) * 8];
            C[mt] = __builtin_amdgcn_mfma_f32_16x16x32_bf16(A, B, C[mt], 0, 0, 0);
        }
    }

    int colc = w * 16 + ln;
    float bb = b2[colc];
    float pe = 0.f;
#pragma unroll
    for (int mt = 0; mt < 4; mt++)
#pragma unroll
        for (int r = 0; r < 4; r++) {
            int row = mt * 16 + lg * 4 + r;
            pe += mask[n * 64 + row] * (C[mt][r] + bb);
        }
    pe += __shfl_xor(pe, 16, 64);
    pe += __shfl_xor(pe, 32, 64);
    if (lg == 0) out[(size_t)n * 64 + colc] = pe;
}

// ---------------- host launch ----------------
extern "C" void kernel_launch(void* const* d_in, const int* in_sizes, int n_in, void* d_out, int out_size,
                              void* d_ws, size_t ws_size, hipStream_t stream) {
    const float* W    = (const float*)d_in[0];
    const float* mask = (const float*)d_in[1];
    const int* src    = (const int*)d_in[2];
    const int* dst    = (const int*)d_in[3];
    const float* eps  = (const float*)d_in[4];
    const float* W1f  = (const float*)d_in[5];
    const float* b1f  = (const float*)d_in[6];
    const float* W1r  = (const float*)d_in[7];
    const float* b1r  = (const float*)d_in[8];
    const float* gam  = (const float*)d_in[9];
    const float* bet  = (const float*)d_in[10];
    const float* W2m  = (const float*)d_in[11];
    const float* b2m  = (const float*)d_in[12];
    const float* W2l  = (const float*)d_in[13];
    const float* b2l  = (const float*)d_in[14];
    float* out = (float*)d_out;

    // workspace layout
    ushort_t* Ha   = (ushort_t*)d_ws;          // 16,777,216
    ushort_t* Hb   = Ha + 16777216;            // 16,777,216
    ushort_t* w1t0 = Hb + 16777216;            // 4096
    ushort_t* w2lt = w1t0 + 4096;              // 8192
    ushort_t* w21t = w2lt + 8192;              // 49152
    float* bvec    = (float*)(w21t + 49152);   // 384
    int* ideg      = (int*)(bvec + 384);       // 2048
    int* icur      = ideg + 2048;              // 2048
    float* sums    = (float*)(icur + 2048);    // 4 layers x NSLOT x 256 = 16384 (zeroed with ideg/icur)
    int* irp       = (int*)(sums + 16384);     // 2049
    int* icol      = irp + 2052;               // 16384

    // zero deg/cursor/sums in one kernel (contiguous 2048+2048+16384 = 20480 words)
    zero_ints<<<80, 256, 0, stream>>>(ideg, 20480);
    count_deg<<<NEDGE / 256, 256, 0, stream>>>(dst, ideg);
    scan_deg<<<1, 256, 0, stream>>>(ideg, irp);
    fill_csr<<<NEDGE / 256, 256, 0, stream>>>(src, dst, irp, icur, icol);
    prep_small<<<50, 256, 0, stream>>>(W1f, W2l, b2m, W1r, w1t0, w2lt, bvec);
    prep_w21<<<192, 256, 0, stream>>>(W2m, W1r, w21t);

    // layer 0 (stats -> sums slots [0])
    gin_mm1_l0<<<N_SUM, 256, 0, stream>>>(W, w1t0, b1f, eps, irp, icol, Ha, sums);
    // layers 1..3 (consume slots[l-1], produce slots[l])
    gin_mm1_fused<<<N_SUM, 512, 0, stream>>>(Ha, w21t, b1r, bvec, sums, gam, bet, eps + 1,
                                             irp, icol, Hb, sums + NSLOT * 256);
    gin_mm1_fused<<<N_SUM, 512, 0, stream>>>(Hb, w21t + 16384, b1r + 128, bvec + 128, sums + NSLOT * 256,
                                             gam + 128, bet + 128, eps + 2, irp, icol, Ha, sums + 2 * NSLOT * 256);
    gin_mm1_fused<<<N_SUM, 512, 0, stream>>>(Ha, w21t + 32768, b1r + 256, bvec + 256, sums + 2 * NSLOT * 256,
                                             gam + 256, bet + 256, eps + 3, irp, icol, Hb, sums + 3 * NSLOT * 256);
    // final (consumes slots[3])
    gin_mm2_last<<<N_SUM, 256, 0, stream>>>(Hb, w2lt, b2l, sums + 3 * NSLOT * 256, gam + 384, bet + 384, mask, out);
}